// Round 1
// baseline (314.574 us; speedup 1.0000x reference)
//
#include <hip/hip_runtime.h>

// ---------------------------------------------------------------------------
// DensityMatrixMLP: out[b] = (L Lt) / trace(L Lt),  L = tril(relu(x@W1+b1)@W2+b2)
// B=131072, IN=256, HID=128, TRIL=136, D=16.
//
// Memory floor: read x (134MB) + write out (134MB) = 268MB -> ~42.5us @6.3TB/s.
// GEMMs on fp16 MFMA (fp32 accum) to get off the fp32 VALU (no fp32 MFMA).
// Error budget: out = rho/trace, trace~68 shrinks abs errors; fp16 chain gives
// ~1e-3 absmax vs 7.4e-3 threshold.
// ---------------------------------------------------------------------------

typedef _Float16 h8 __attribute__((ext_vector_type(8)));
typedef float    f4 __attribute__((ext_vector_type(4)));

#define BATCH_N 131072
#define IN_DIM  256
#define HID     128
#define TRILN   136
#define BM      128      // batch rows per block (4 waves x 2 m-tiles of 16)
#define NT1     8        // 128/16 n-tiles, GEMM1
#define KS1     8        // 256/32 k-steps, GEMM1
#define NT2     9        // ceil(136/16) n-tiles, GEMM2 (padded with zeros)
#define KS2     4        // 128/32 k-steps, GEMM2
#define HSTR    136      // h LDS row stride (halves): 272B = 68 banks == 4 mod 32
#define VSTR    137      // v LDS row stride (floats): odd -> conflict-free scalar reads
#define PW1_N   (KS1*NT1*64*8)   // 32768 halves = 64 KB
#define PW2_N   (KS2*NT2*64*8)   // 18432 halves = 36 KB

// ---------------------------------------------------------------------------
// Prelude: pack W1/W2 into MFMA B-fragment order, fp16.
// B-frag layout for mfma_f32_16x16x32_f16: lane holds B[k=(lane>>4)*8+j][n=lane&15],
// j=0..7 contiguous. Packed: pw[((ks*NT+nt)*64+lane)*8+j] -> one dwordx4/lane.
// ---------------------------------------------------------------------------
__global__ void pack_weights(const float* __restrict__ W1,
                             const float* __restrict__ W2,
                             _Float16* __restrict__ pw1,
                             _Float16* __restrict__ pw2) {
    int gid = blockIdx.x * blockDim.x + threadIdx.x;
    if (gid < PW1_N) {
        int j = gid & 7, l = (gid >> 3) & 63, f = gid >> 9;
        int ks = f >> 3, nt = f & 7;
        int k = ks * 32 + (l >> 4) * 8 + j;
        int n = nt * 16 + (l & 15);
        pw1[gid] = (_Float16)W1[k * HID + n];
    } else if (gid < PW1_N + PW2_N) {
        int g = gid - PW1_N;
        int j = g & 7, l = (g >> 3) & 63, f = g >> 9;
        int ks = f / NT2, nt = f - ks * NT2;
        int k = ks * 32 + (l >> 4) * 8 + j;
        int col = nt * 16 + (l & 15);
        pw2[g] = (col < TRILN) ? (_Float16)W2[k * TRILN + col] : (_Float16)0.0f;
    }
}

__device__ __forceinline__ h8 cvt_h8(f4 lo, f4 hi) {
    h8 r;
    r[0] = (_Float16)lo[0]; r[1] = (_Float16)lo[1];
    r[2] = (_Float16)lo[2]; r[3] = (_Float16)lo[3];
    r[4] = (_Float16)hi[0]; r[5] = (_Float16)hi[1];
    r[6] = (_Float16)hi[2]; r[7] = (_Float16)hi[3];
    return r;
}

// ---------------------------------------------------------------------------
// Epilogue: lane = row (0..63) of the current 64-row phase; wave W computes
// output columns i in {W, 7-W, W+8, 15-W} (balanced work, all bounds static,
// wave-uniform dispatch -> no divergence).
// rho[i][j] = sum_{k<=min(i,j)} v[ti+k]*v[tj+k];  out = rho / trace.
// ---------------------------------------------------------------------------
template<int W>
__device__ __forceinline__ void epi(const float* vb, int lane, float* outb) {
    constexpr int I0 = W, I1 = 7 - W, I2 = W + 8, I3 = 15 - W;
    constexpr int T0 = I0*(I0+1)/2, T1 = I1*(I1+1)/2, T2 = I2*(I2+1)/2, T3 = I3*(I3+1)/2;
    const float* vr = vb + lane * VSTR;

    // trace = sum of squares of all 136 tril entries (2 accumulators for ILP)
    float ta = 0.f, tb = 0.f;
    #pragma unroll
    for (int c = 0; c < TRILN; c += 2) {
        float x0 = vr[c], x1 = vr[c + 1];
        ta += x0 * x0; tb += x1 * x1;
    }
    float rinv = 1.0f / (ta + tb);

    // cache our 4 L-rows in registers (static lengths)
    float li0[I0 + 1], li1[I1 + 1], li2[I2 + 1], li3[I3 + 1];
    #pragma unroll
    for (int k = 0; k <= I0; ++k) li0[k] = vr[T0 + k];
    #pragma unroll
    for (int k = 0; k <= I1; ++k) li1[k] = vr[T1 + k];
    #pragma unroll
    for (int k = 0; k <= I2; ++k) li2[k] = vr[T2 + k];
    #pragma unroll
    for (int k = 0; k <= I3; ++k) li3[k] = vr[T3 + k];

    float r0[16], r1[16], r2[16], r3[16];
    #pragma unroll
    for (int j = 0; j < 16; ++j) {
        const int tj = j * (j + 1) / 2;
        float vj[16];
        #pragma unroll
        for (int k = 0; k <= j; ++k) vj[k] = vr[tj + k];
        { const int m = (I0 < j) ? I0 : j; float s = 0.f;
          #pragma unroll
          for (int k = 0; k <= m; ++k) s += li0[k] * vj[k];
          r0[j] = s * rinv; }
        { const int m = (I1 < j) ? I1 : j; float s = 0.f;
          #pragma unroll
          for (int k = 0; k <= m; ++k) s += li1[k] * vj[k];
          r1[j] = s * rinv; }
        { const int m = (I2 < j) ? I2 : j; float s = 0.f;
          #pragma unroll
          for (int k = 0; k <= m; ++k) s += li2[k] * vj[k];
          r2[j] = s * rinv; }
        { const int m = (I3 < j) ? I3 : j; float s = 0.f;
          #pragma unroll
          for (int k = 0; k <= m; ++k) s += li3[k] * vj[k];
          r3[j] = s * rinv; }
    }
    float* op = outb + lane * 256;
    #pragma unroll
    for (int jq = 0; jq < 4; ++jq) {
        *(f4*)(op + I0 * 16 + jq * 4) = (f4){r0[4*jq], r0[4*jq+1], r0[4*jq+2], r0[4*jq+3]};
        *(f4*)(op + I1 * 16 + jq * 4) = (f4){r1[4*jq], r1[4*jq+1], r1[4*jq+2], r1[4*jq+3]};
        *(f4*)(op + I2 * 16 + jq * 4) = (f4){r2[4*jq], r2[4*jq+1], r2[4*jq+2], r2[4*jq+3]};
        *(f4*)(op + I3 * 16 + jq * 4) = (f4){r3[4*jq], r3[4*jq+1], r3[4*jq+2], r3[4*jq+3]};
    }
}

// ---------------------------------------------------------------------------
// Fused kernel: 256 threads (4 waves), 128 batch rows/block.
// GEMM1 A-frags straight from global x (fp32->fp16 in regs, x read exactly once),
// B-frags from packed fp16 arrays (L1/L2-resident). h via LDS (fp16), v via LDS
// (fp32, overlaid on h, two 64-row phases), epilogue in fp32 VALU.
// ---------------------------------------------------------------------------
__global__ __launch_bounds__(256, 2) void fused_mlp(
        const float* __restrict__ x, const float* __restrict__ b1,
        const float* __restrict__ b2, const _Float16* __restrict__ pw1,
        const _Float16* __restrict__ pw2, float* __restrict__ out) {
    __shared__ char smem_raw[64 * VSTR * 4] __attribute__((aligned(16)));  // 35072 B
    _Float16* hbuf = (_Float16*)smem_raw;  // [128][HSTR] halves (34816 B)
    float*    vbuf = (float*)smem_raw;     // [64][VSTR] floats (overlaid)

    const int tid  = threadIdx.x;
    const int w    = tid >> 6;
    const int lane = tid & 63;
    const int q    = lane >> 4;
    const int lm   = lane & 15;
    const int b0   = blockIdx.x * BM;

    // ---------------- GEMM1: h = relu(x @ W1 + b1) ----------------
    f4 acc1[2][NT1];
    #pragma unroll
    for (int mt = 0; mt < 2; ++mt)
        #pragma unroll
        for (int nt = 0; nt < NT1; ++nt)
            acc1[mt][nt] = (f4){0.f, 0.f, 0.f, 0.f};

    const float* xr0 = x + (size_t)(b0 + w * 16 + lm) * IN_DIM + q * 8;  // m-tile 0
    const float* xr1 = xr0 + (size_t)64 * IN_DIM;                        // m-tile 1

    f4 a0l = *(const f4*)xr0, a0h = *(const f4*)(xr0 + 4);
    f4 a1l = *(const f4*)xr1, a1h = *(const f4*)(xr1 + 4);

    #pragma unroll
    for (int ks = 0; ks < KS1; ++ks) {
        h8 bf[NT1];
        #pragma unroll
        for (int nt = 0; nt < NT1; ++nt)
            bf[nt] = *(const h8*)(pw1 + ((ks * NT1 + nt) * 64 + lane) * 8);
        h8 af0 = cvt_h8(a0l, a0h);
        h8 af1 = cvt_h8(a1l, a1h);
        if (ks + 1 < KS1) {  // prefetch next k-step of x (the HBM stream)
            const float* p0 = xr0 + (ks + 1) * 32;
            const float* p1 = xr1 + (ks + 1) * 32;
            a0l = *(const f4*)p0; a0h = *(const f4*)(p0 + 4);
            a1l = *(const f4*)p1; a1h = *(const f4*)(p1 + 4);
        }
        #pragma unroll
        for (int nt = 0; nt < NT1; ++nt) {
            acc1[0][nt] = __builtin_amdgcn_mfma_f32_16x16x32_f16(af0, bf[nt], acc1[0][nt], 0, 0, 0);
            acc1[1][nt] = __builtin_amdgcn_mfma_f32_16x16x32_f16(af1, bf[nt], acc1[1][nt], 0, 0, 0);
        }
    }

    // bias + relu + store h to LDS as fp16 (each wave touches only its own rows)
    {
        float b1v[NT1];
        #pragma unroll
        for (int nt = 0; nt < NT1; ++nt) b1v[nt] = b1[nt * 16 + lm];
        #pragma unroll
        for (int mt = 0; mt < 2; ++mt)
            #pragma unroll
            for (int nt = 0; nt < NT1; ++nt)
                #pragma unroll
                for (int r = 0; r < 4; ++r) {
                    float hv = acc1[mt][nt][r] + b1v[nt];
                    hv = fmaxf(hv, 0.f);
                    // C-layout: row = q*4+r, col = lm
                    hbuf[(mt * 64 + w * 16 + q * 4 + r) * HSTR + nt * 16 + lm] = (_Float16)hv;
                }
    }

    // ---------------- GEMM2: v = h @ W2 + b2 ----------------
    f4 acc2[2][NT2];
    #pragma unroll
    for (int mt = 0; mt < 2; ++mt)
        #pragma unroll
        for (int nt = 0; nt < NT2; ++nt)
            acc2[mt][nt] = (f4){0.f, 0.f, 0.f, 0.f};

    #pragma unroll
    for (int ks = 0; ks < KS2; ++ks) {
        // A-layout: row = lm, k = ks*32 + q*8 .. +7 (16B-aligned ds_read_b128)
        h8 ha0 = *(const h8*)(hbuf + (w * 16 + lm) * HSTR + ks * 32 + q * 8);
        h8 ha1 = *(const h8*)(hbuf + (64 + w * 16 + lm) * HSTR + ks * 32 + q * 8);
        #pragma unroll
        for (int nt = 0; nt < NT2; ++nt) {
            h8 bf = *(const h8*)(pw2 + ((ks * NT2 + nt) * 64 + lane) * 8);
            acc2[0][nt] = __builtin_amdgcn_mfma_f32_16x16x32_f16(ha0, bf, acc2[0][nt], 0, 0, 0);
            acc2[1][nt] = __builtin_amdgcn_mfma_f32_16x16x32_f16(ha1, bf, acc2[1][nt], 0, 0, 0);
        }
    }

    float b2v[NT2];
    #pragma unroll
    for (int nt = 0; nt < NT2; ++nt) {
        int col = nt * 16 + lm;
        b2v[nt] = (col < TRILN) ? b2[col] : 0.f;
    }

    // ---------------- two 64-row phases: v -> LDS, then LL^T epilogue ----------
    #pragma unroll 1   // keep rolled: halves code size (epi templates shared)
    for (int mt = 0; mt < 2; ++mt) {
        __syncthreads();  // mt=0: protect hbuf readers; mt=1: protect phase-A v readers
        #pragma unroll
        for (int nt = 0; nt < NT2; ++nt) {
            int col = nt * 16 + lm;
            if (col < TRILN) {
                #pragma unroll
                for (int r = 0; r < 4; ++r) {
                    f4 t = (mt == 0) ? acc2[0][nt] : acc2[1][nt];
                    vbuf[(w * 16 + q * 4 + r) * VSTR + col] = t[r] + b2v[nt];
                }
            }
        }
        __syncthreads();
        float* outbase = out + (size_t)(b0 + mt * 64) * 256;
        switch (w) {  // wave-uniform -> no divergence
            case 0:  epi<0>(vbuf, lane, outbase); break;
            case 1:  epi<1>(vbuf, lane, outbase); break;
            case 2:  epi<2>(vbuf, lane, outbase); break;
            default: epi<3>(vbuf, lane, outbase); break;
        }
    }
}

extern "C" void kernel_launch(void* const* d_in, const int* in_sizes, int n_in,
                              void* d_out, int out_size, void* d_ws, size_t ws_size,
                              hipStream_t stream) {
    const float* x  = (const float*)d_in[0];
    const float* W1 = (const float*)d_in[1];
    const float* b1 = (const float*)d_in[2];
    const float* W2 = (const float*)d_in[3];
    const float* b2 = (const float*)d_in[4];
    float* out = (float*)d_out;

    _Float16* pw1 = (_Float16*)d_ws;            // 64 KB
    _Float16* pw2 = pw1 + PW1_N;                // 36 KB  (needs ws_size >= 100 KB)

    pack_weights<<<(PW1_N + PW2_N + 255) / 256, 256, 0, stream>>>(W1, W2, pw1, pw2);
    fused_mlp<<<BATCH_N / BM, 256, 0, stream>>>(x, b1, b2, pw1, pw2, out);
}

// Round 2
// 263.838 us; speedup vs baseline: 1.1923x; 1.1923x over previous
//
#include <hip/hip_runtime.h>

// ---------------------------------------------------------------------------
// DensityMatrixMLP: out[b] = (L Lt) / trace(L Lt),  L = tril(relu(x@W1+b1)@W2+b2)
// B=131072, IN=256, HID=128, TRIL=136, D=16.
//
// R1: VALU epilogue (300 ds_read_b32 + 1900 FMA per lane-phase) + scattered
// 16B stores made the kernel issue-bound (13% BW, 8.5% VALU, 152us).
// R2: LL^T via MFMA. Key identity: for C = L*L^T, the A-frag and B-frag of
// mfma_16x16x32_f16 are the SAME fragment (lane holds L[lm][q*8+j]).
// v stored once to LDS as fp16 (rows 4-half aligned), trace from registers
// via shfl_xor, scale via readlane, stores cover full 64B sectors.
// ---------------------------------------------------------------------------

typedef _Float16 h8 __attribute__((ext_vector_type(8)));
typedef float    f4 __attribute__((ext_vector_type(4)));
typedef int      i2 __attribute__((ext_vector_type(2)));

#define BATCH_N 131072
#define IN_DIM  256
#define HID     128
#define TRILN   136
#define BM      128      // batch rows per block (4 waves x 2 m-tiles of 16)
#define NT1     8        // 128/16 n-tiles, GEMM1
#define KS1     8        // 256/32 k-steps, GEMM1
#define NT2     9        // ceil(136/16) n-tiles, GEMM2 (padded with zeros)
#define KS2     4        // 128/32 k-steps, GEMM2
#define HSTR    136      // h LDS row stride (halves)
#define LVSTR   160      // v LDS row stride (halves): 16 tril rows, each padded
                         // to 4-half multiple -> every L-row starts 8B-aligned
#define PW1_N   (KS1*NT1*64*8)   // 32768 halves = 64 KB
#define PW2_N   (KS2*NT2*64*8)   // 18432 halves = 36 KB

// offset (halves) of tril row i inside a batch row's LVSTR region:
// rows padded to 4*ceil((i+1)/4); closed form via group g=i>>2.
__device__ __forceinline__ int rowoff(int i) {
    int g = i >> 2;
    return 4 * (g + 1) * (2 * g + (i & 3));   // 0,4,8,12,16,24,...,144
}

// ---------------------------------------------------------------------------
// Prelude: pack W1/W2 into MFMA B-fragment order, fp16.
// ---------------------------------------------------------------------------
__global__ void pack_weights(const float* __restrict__ W1,
                             const float* __restrict__ W2,
                             _Float16* __restrict__ pw1,
                             _Float16* __restrict__ pw2) {
    int gid = blockIdx.x * blockDim.x + threadIdx.x;
    if (gid < PW1_N) {
        int j = gid & 7, l = (gid >> 3) & 63, f = gid >> 9;
        int ks = f >> 3, nt = f & 7;
        int k = ks * 32 + (l >> 4) * 8 + j;
        int n = nt * 16 + (l & 15);
        pw1[gid] = (_Float16)W1[k * HID + n];
    } else if (gid < PW1_N + PW2_N) {
        int g = gid - PW1_N;
        int j = g & 7, l = (g >> 3) & 63, f = g >> 9;
        int ks = f / NT2, nt = f - ks * NT2;
        int k = ks * 32 + (l >> 4) * 8 + j;
        int col = nt * 16 + (l & 15);
        pw2[g] = (col < TRILN) ? (_Float16)W2[k * TRILN + col] : (_Float16)0.0f;
    }
}

__device__ __forceinline__ h8 cvt_h8(f4 lo, f4 hi) {
    h8 r;
    r[0] = (_Float16)lo[0]; r[1] = (_Float16)lo[1];
    r[2] = (_Float16)lo[2]; r[3] = (_Float16)lo[3];
    r[4] = (_Float16)hi[0]; r[5] = (_Float16)hi[1];
    r[6] = (_Float16)hi[2]; r[7] = (_Float16)hi[3];
    return r;
}

// ---------------------------------------------------------------------------
// Fused kernel: 256 threads (4 waves), 128 batch rows/block, ONE barrier.
// ---------------------------------------------------------------------------
__global__ __launch_bounds__(256, 4) void fused_mlp(
        const float* __restrict__ x, const float* __restrict__ b1,
        const float* __restrict__ b2, const _Float16* __restrict__ pw1,
        const _Float16* __restrict__ pw2, float* __restrict__ out) {
    __shared__ char smem_raw[BM * LVSTR * 2] __attribute__((aligned(16)));  // 40960 B
    _Float16* hbuf = (_Float16*)smem_raw;  // [128][HSTR] halves (GEMM1->GEMM2)
    _Float16* lv   = (_Float16*)smem_raw;  // [128][LVSTR] halves (overlaid, post-barrier)

    const int tid  = threadIdx.x;
    const int w    = tid >> 6;
    const int lane = tid & 63;
    const int q    = lane >> 4;
    const int lm   = lane & 15;
    const int b0   = blockIdx.x * BM;

    // ---------------- GEMM1: h = relu(x @ W1 + b1) ----------------
    f4 acc1[2][NT1];
    #pragma unroll
    for (int mt = 0; mt < 2; ++mt)
        #pragma unroll
        for (int nt = 0; nt < NT1; ++nt)
            acc1[mt][nt] = (f4){0.f, 0.f, 0.f, 0.f};

    const float* xr0 = x + (size_t)(b0 + w * 16 + lm) * IN_DIM + q * 8;  // m-tile 0
    const float* xr1 = xr0 + (size_t)64 * IN_DIM;                        // m-tile 1

    f4 a0l = *(const f4*)xr0, a0h = *(const f4*)(xr0 + 4);
    f4 a1l = *(const f4*)xr1, a1h = *(const f4*)(xr1 + 4);

    #pragma unroll
    for (int ks = 0; ks < KS1; ++ks) {
        h8 bf[NT1];
        #pragma unroll
        for (int nt = 0; nt < NT1; ++nt)
            bf[nt] = *(const h8*)(pw1 + ((ks * NT1 + nt) * 64 + lane) * 8);
        h8 af0 = cvt_h8(a0l, a0h);
        h8 af1 = cvt_h8(a1l, a1h);
        if (ks + 1 < KS1) {  // prefetch next k-step of x (the HBM stream)
            const float* p0 = xr0 + (ks + 1) * 32;
            const float* p1 = xr1 + (ks + 1) * 32;
            a0l = *(const f4*)p0; a0h = *(const f4*)(p0 + 4);
            a1l = *(const f4*)p1; a1h = *(const f4*)(p1 + 4);
        }
        #pragma unroll
        for (int nt = 0; nt < NT1; ++nt) {
            acc1[0][nt] = __builtin_amdgcn_mfma_f32_16x16x32_f16(af0, bf[nt], acc1[0][nt], 0, 0, 0);
            acc1[1][nt] = __builtin_amdgcn_mfma_f32_16x16x32_f16(af1, bf[nt], acc1[1][nt], 0, 0, 0);
        }
    }

    // bias + relu + store h to LDS as fp16 (own rows only -> no barrier)
    {
        float b1v[NT1];
        #pragma unroll
        for (int nt = 0; nt < NT1; ++nt) b1v[nt] = b1[nt * 16 + lm];
        #pragma unroll
        for (int mt = 0; mt < 2; ++mt)
            #pragma unroll
            for (int nt = 0; nt < NT1; ++nt)
                #pragma unroll
                for (int r = 0; r < 4; ++r) {
                    float hv = acc1[mt][nt][r] + b1v[nt];
                    hv = fmaxf(hv, 0.f);
                    hbuf[(mt * 64 + w * 16 + q * 4 + r) * HSTR + nt * 16 + lm] = (_Float16)hv;
                }
    }

    // ---------------- GEMM2: v = h @ W2 + b2 ----------------
    f4 acc2[2][NT2];
    #pragma unroll
    for (int mt = 0; mt < 2; ++mt)
        #pragma unroll
        for (int nt = 0; nt < NT2; ++nt)
            acc2[mt][nt] = (f4){0.f, 0.f, 0.f, 0.f};

    #pragma unroll
    for (int ks = 0; ks < KS2; ++ks) {
        h8 ha0 = *(const h8*)(hbuf + (w * 16 + lm) * HSTR + ks * 32 + q * 8);
        h8 ha1 = *(const h8*)(hbuf + (64 + w * 16 + lm) * HSTR + ks * 32 + q * 8);
        #pragma unroll
        for (int nt = 0; nt < NT2; ++nt) {
            h8 bf = *(const h8*)(pw2 + ((ks * NT2 + nt) * 64 + lane) * 8);
            acc2[0][nt] = __builtin_amdgcn_mfma_f32_16x16x32_f16(ha0, bf, acc2[0][nt], 0, 0, 0);
            acc2[1][nt] = __builtin_amdgcn_mfma_f32_16x16x32_f16(ha1, bf, acc2[1][nt], 0, 0, 0);
        }
    }

    float b2v[NT2];
    #pragma unroll
    for (int nt = 0; nt < NT2; ++nt) {
        int col = nt * 16 + lm;
        b2v[nt] = (col < TRILN) ? b2[col] : 0.f;
    }

    // trace partials from registers: ps[mt][r] = sum over this lane's cols of v^2
    float ps[2][4];
    #pragma unroll
    for (int mt = 0; mt < 2; ++mt)
        #pragma unroll
        for (int r = 0; r < 4; ++r) ps[mt][r] = 0.f;
    #pragma unroll
    for (int mt = 0; mt < 2; ++mt)
        #pragma unroll
        for (int nt = 0; nt < NT2; ++nt)
            #pragma unroll
            for (int r = 0; r < 4; ++r) {
                float v = acc2[mt][nt][r] + b2v[nt];   // cols>=136 contribute 0
                ps[mt][r] += v * v;
            }

    // reduce across the 16 lanes (same q) holding one row's columns
    float rinv[2][4];
    #pragma unroll
    for (int mt = 0; mt < 2; ++mt)
        #pragma unroll
        for (int r = 0; r < 4; ++r) {
            float s = ps[mt][r];
            s += __shfl_xor(s, 1);
            s += __shfl_xor(s, 2);
            s += __shfl_xor(s, 4);
            s += __shfl_xor(s, 8);
            rinv[mt][r] = 1.0f / s;
        }

    // per-lane tril mapping for the 9 columns this lane owns: col c -> (i,k)
    int voff[NT2];
    bool vok[NT2];
    #pragma unroll
    for (int nt = 0; nt < NT2; ++nt) {
        int c = nt * 16 + lm;
        vok[nt] = (c < TRILN);
        int cc = vok[nt] ? c : 0;
        int i = (int)((sqrtf(8.0f * (float)cc + 1.0f) - 1.0f) * 0.5f);
        int k = cc - (i * (i + 1)) / 2;
        voff[nt] = rowoff(i) + k;
    }

    __syncthreads();   // all GEMM2 hbuf reads done before lv overlays it

    // scatter v (fp16) into padded-tril LDS layout (own rows only)
    #pragma unroll
    for (int mt = 0; mt < 2; ++mt)
        #pragma unroll
        for (int r = 0; r < 4; ++r) {
            int base = (mt * 64 + w * 16 + q * 4 + r) * LVSTR;
            #pragma unroll
            for (int nt = 0; nt < NT2; ++nt)
                if (vok[nt])
                    lv[base + voff[nt]] = (_Float16)(acc2[mt][nt][r] + b2v[nt]);
        }

    // frag masks: element j of the frag is L[lm][q*8+j], valid iff q*8+j <= lm
    int msk[4];
    {
        int n = lm - q * 8 + 1;           // number of valid j's (clamped below)
        #pragma unroll
        for (int p = 0; p < 4; ++p) {
            int c2 = n - 2 * p; c2 = c2 < 0 ? 0 : (c2 > 2 ? 2 : c2);
            msk[p] = (c2 == 2) ? ~0 : ((c2 == 1) ? 0xFFFF : 0);
        }
    }
    const int ro_lm = rowoff(lm);
    const f4 zero = (f4){0.f, 0.f, 0.f, 0.f};
    const int outcol = q * 64 + lm;       // (q*4)*16 + lm

    // ---------------- LL^T via MFMA: one frag per batch row ----------------
    // (own rows; within-wave ds ordering makes our scatter writes visible)
    #pragma unroll
    for (int mt = 0; mt < 2; ++mt)
        #pragma unroll
        for (int tq = 0; tq < 4; ++tq)
            #pragma unroll
            for (int r4 = 0; r4 < 4; ++r4) {
                int t = tq * 4 + r4;
                int row = mt * 64 + w * 16 + t;
                const _Float16* rp = lv + row * LVSTR + ro_lm + q * 8;
                i2 lo = *(const i2*)rp;
                i2 hi = *(const i2*)(rp + 4);
                h8 frag;
                ((i2*)&frag)[0] = (i2){lo.x & msk[0], lo.y & msk[1]};
                ((i2*)&frag)[1] = (i2){hi.x & msk[2], hi.y & msk[3]};
                f4 d = __builtin_amdgcn_mfma_f32_16x16x32_f16(frag, frag, zero, 0, 0, 0);
                float riv = __uint_as_float(
                    __builtin_amdgcn_readlane(__float_as_uint(rinv[mt][r4]), tq * 16));
                float* op = out + (size_t)(b0 + row) * 256 + outcol;
                #pragma unroll
                for (int sr = 0; sr < 4; ++sr)
                    op[sr * 16] = d[sr] * riv;   // full 64B sectors per instr
            }
}

extern "C" void kernel_launch(void* const* d_in, const int* in_sizes, int n_in,
                              void* d_out, int out_size, void* d_ws, size_t ws_size,
                              hipStream_t stream) {
    const float* x  = (const float*)d_in[0];
    const float* W1 = (const float*)d_in[1];
    const float* b1 = (const float*)d_in[2];
    const float* W2 = (const float*)d_in[3];
    const float* b2 = (const float*)d_in[4];
    float* out = (float*)d_out;

    _Float16* pw1 = (_Float16*)d_ws;            // 64 KB
    _Float16* pw2 = pw1 + PW1_N;                // 36 KB  (needs ws_size >= 100 KB)

    pack_weights<<<(PW1_N + PW2_N + 255) / 256, 256, 0, stream>>>(W1, W2, pw1, pw2);
    fused_mlp<<<BATCH_N / BM, 256, 0, stream>>>(x, b1, b2, pw1, pw2, out);
}